// Round 5
// baseline (1010.019 us; speedup 1.0000x reference)
//
#include <hip/hip_runtime.h>

#define NTOT  10000
#define TALL  64
#define TCTX  24
#define HOR   40
#define HH    128
#define G4    512
#define NENV  17
#define SAMP  16

typedef __attribute__((ext_vector_type(8))) short  bf16x8;
typedef __attribute__((ext_vector_type(4))) float  f32x4;
typedef unsigned short u16;

// ---- ws fragment segments (units of 16-byte frags; ws byte offset = fid*16) ----
#define SEG_W0E   0        // enc_Whh layer0
#define SEG_W0D   8192     // in_Whh
#define SEG_WIH1  16384    // enc_Wih layer1
#define SEG_WHH1  24576    // enc_Whh layer1
#define SEG_DWIH  32768    // dWih
#define SEG_DWHH  40960    // dWhh
#define SEG_M0E   49152    // M0-extended (K=32)
#define SEG_MDE   51200    // Md-extended
#define SEG_WIHH  53248    // in_Wih[:,128:]
#define SEG_W1H   61440    // mlp_W1[:,:128]
#define SEG_W1I   63488    // W1-extended (K=32)
#define NFRAGS    64000

// LDS layout (bytes)
#define L_MDL   0          // 32768 : M0E/MDE frags
#define L_W1H   32768      // 32768
#define L_W1I   65536      // 8192
#define L_BASE  73728      // 32768 : baseD f32
#define L_H0    106496     // 2 x 4352 (double-buffered)
#define L_H1    115200     // 2 x 4352
#define L_ZMS   123904     // 4352
#define L_INPS  128256     // 1280 : 16 x 40 u16
#define L_XBLK  129536     // 1536 : 16 x 24 f32
#define L_W2L   131072     // 1024 : 256 f32
#define L_XCS   132096     // 64
#define SMEM_TOTAL 132160

__device__ __forceinline__ float sigf(float v)   { return 1.0f/(1.0f + __expf(-v)); }
__device__ __forceinline__ float tanhf_(float v) { return 1.0f - 2.0f/(__expf(2.0f*v) + 1.0f); }
__device__ __forceinline__ u16 f2bf(float f){
    unsigned int u = __float_as_uint(f);
    u += 0x7fffu + ((u >> 16) & 1u);
    return (u16)(u >> 16);
}
__device__ __forceinline__ float bf2f(u16 h){ return __uint_as_float(((unsigned int)h) << 16); }

// =====================  fold: build all bf16 fragment-packed weights  =====================
// inp32 column order: [0..16]=env, 17=x, 18=cd0, 19=cd1, 20=areas, 21=1(bias), 22..31=0
__global__ void fold_kernel(const float* __restrict__ enc_Wih, const float* __restrict__ enc_Whh,
                            const float* __restrict__ W_enc_in,
                            const float* __restrict__ in_Wih,  const float* __restrict__ in_Whh,
                            const float* __restrict__ W_dec_in,
                            const float* __restrict__ dWih,    const float* __restrict__ dWhh,
                            const float* __restrict__ mlp_W1,  const float* __restrict__ mlp_b1,
                            const float* __restrict__ enc_bih, const float* __restrict__ enc_bhh,
                            const float* __restrict__ in_bih,  const float* __restrict__ in_bhh,
                            void* __restrict__ ws)
{
    int fid = blockIdx.x*256 + threadIdx.x;
    if (fid >= NFRAGS) return;
    const int lane = fid & 63;
    const int cc = lane & 15;
    const int kg = lane >> 4;
    float vals[8];

    if (fid < 49152) {                       // six plain K=128 matrices
        int segi = fid >> 13;
        int loc  = fid & 8191;
        int gt   = loc >> 8;
        int kb   = (loc >> 6) & 3;
        int r    = gt*16 + cc;
        int k0   = kb*32 + kg*8;
        const float* src;
        switch (segi) {
            case 0: src = enc_Whh;          break;
            case 1: src = in_Whh;           break;
            case 2: src = enc_Wih + 65536;  break;
            case 3: src = enc_Whh + 65536;  break;
            case 4: src = dWih;             break;
            default: src = dWhh;            break;
        }
        #pragma unroll
        for (int j = 0; j < 8; ++j) vals[j] = src[(size_t)r*128 + k0 + j];
    } else if (fid < 53248) {                // M0E / MDE extended-input (K=32, folded chain)
        int loc = fid - 49152;
        int which = loc >> 11; loc &= 2047;
        int gt = loc >> 6;
        int r  = gt*16 + cc;
        int k0 = kg*8;
        const float* A = which ? (in_Wih + (size_t)r*256) : (enc_Wih + (size_t)r*128);
        const float* B = which ? W_dec_in : W_enc_in;
        float bias = which ? (in_bih[r] + in_bhh[r]) : (enc_bih[r] + enc_bhh[r]);
        #pragma unroll
        for (int j = 0; j < 8; ++j) {
            int k = k0 + j;
            float v = 0.f;
            int c = (k <= 16) ? (3 + k) : (k == 17 ? 0 : (k == 18 ? 1 : (k == 19 ? 2 : (k == 20 ? 20 : -1))));
            if (k == 21) v = bias;
            else if (c >= 0) {
                float a = 0.f;
                for (int h = 0; h < HH; ++h) a = fmaf(A[h], B[h*21 + c], a);
                v = a;
            }
            vals[j] = v;
        }
    } else if (fid < 61440) {                // WIHH = in_Wih[:,128:]
        int loc = fid - 53248;
        int gt = loc >> 8; int kb = (loc >> 6) & 3;
        int r = gt*16 + cc; int k0 = kb*32 + kg*8;
        #pragma unroll
        for (int j = 0; j < 8; ++j) vals[j] = in_Wih[(size_t)r*256 + 128 + k0 + j];
    } else if (fid < 63488) {                // W1H = mlp_W1[:,:128]
        int loc = fid - 61440;
        int gt = loc >> 8; int kb = (loc >> 6) & 3;
        int r = gt*16 + cc; int k0 = kb*32 + kg*8;
        #pragma unroll
        for (int j = 0; j < 8; ++j) vals[j] = mlp_W1[(size_t)r*149 + k0 + j];
    } else {                                  // W1I extended (mlp input part + b1)
        int loc = fid - 63488;
        int gt = loc >> 6;
        int r = gt*16 + cc; int k0 = kg*8;
        #pragma unroll
        for (int j = 0; j < 8; ++j) {
            int k = k0 + j; float v = 0.f;
            if (k <= 16)      v = mlp_W1[(size_t)r*149 + 131 + k];
            else if (k == 17) v = mlp_W1[(size_t)r*149 + 128];
            else if (k == 18) v = mlp_W1[(size_t)r*149 + 129];
            else if (k == 19) v = mlp_W1[(size_t)r*149 + 130];
            else if (k == 20) v = mlp_W1[(size_t)r*149 + 148];
            else if (k == 21) v = mlp_b1[r];
            vals[j] = v;
        }
    }
    union { uint4 u4; u16 us[8]; } pk;
    #pragma unroll
    for (int j = 0; j < 8; ++j) pk.us[j] = f2bf(vals[j]);
    *(uint4*)((char*)ws + (size_t)fid*16) = pk.u4;
}

// =====================  main persistent MFMA kernel: 8 waves, reg-resident weights  ==========
// __launch_bounds__(512, 1): 8-wave block => hard cap 256 VGPR, enough to hold all
// 48 weight fragments (192 VGPR) without spilling. (512,2) capped at 128 and spilled
// every fragment to scratch: R3 showed FETCH 86MB / WRITE 105MB of pure spill traffic.
__global__ __launch_bounds__(512, 1)
void lstm_main(const float* __restrict__ x, const float* __restrict__ coords,
               const float* __restrict__ env, const float* __restrict__ areas,
               const float* __restrict__ enc_bih, const float* __restrict__ enc_bhh,
               const float* __restrict__ dbih,   const float* __restrict__ dbhh,
               const float* __restrict__ mlp_W2, const float* __restrict__ mlp_b2,
               const void* __restrict__ ws, float* __restrict__ out)
{
    extern __shared__ char smem[];
    u16*   MdL  = (u16*)(smem + L_MDL);
    u16*   W1Hl = (u16*)(smem + L_W1H);
    u16*   W1Il = (u16*)(smem + L_W1I);
    float* baseL= (float*)(smem + L_BASE);
    u16*   zms  = (u16*)(smem + L_ZMS);
    u16*   inps = (u16*)(smem + L_INPS);
    float* xblk = (float*)(smem + L_XBLK);
    float* w2l  = (float*)(smem + L_W2L);
    float* xcs  = (float*)(smem + L_XCS);

    const int tid  = threadIdx.x;
    const int lane = tid & 63;
    const int wid  = tid >> 6;          // 0..7: unit block (units wid*16..wid*16+15)
    const int cc   = lane & 15;
    const int kg   = lane >> 4;
    const int s0   = blockIdx.x * SAMP;
    const char* wsb = (const char*)ws;
    const f32x4 zero4 = {0.f, 0.f, 0.f, 0.f};

    // ---------------- init LDS staging ----------------
    #pragma unroll
    for (int i = 0; i < 4; ++i) {
        ((uint4*)(smem + L_MDL))[i*512 + tid] = ((const uint4*)wsb)[SEG_M0E + i*512 + tid];
        ((uint4*)(smem + L_W1H))[i*512 + tid] = ((const uint4*)wsb)[SEG_W1H + i*512 + tid];
    }
    ((uint4*)(smem + L_W1I))[tid] = ((const uint4*)wsb)[SEG_W1I + tid];
    for (int i = tid; i < 2176; i += 512) {            // zero h buffers parity-1
        ((u16*)(smem + L_H0 + 4352))[i] = 0;
        ((u16*)(smem + L_H1 + 4352))[i] = 0;
    }
    if (tid < 384) xblk[tid] = x[(size_t)(s0 + tid/24)*TALL + (tid % 24)];
    if (tid < 256) w2l[tid] = mlp_W2[tid];
    if (tid < SAMP) {
        inps[tid*40 + 18] = f2bf(coords[(size_t)(s0+tid)*2 + 0]);
        inps[tid*40 + 19] = f2bf(coords[(size_t)(s0+tid)*2 + 1]);
        inps[tid*40 + 20] = f2bf(areas[s0+tid]);
        inps[tid*40 + 21] = 0x3F80;   // bf16(1.0) -> bias column
        #pragma unroll
        for (int c = 22; c < 32; ++c) inps[tid*40 + c] = 0;
    }

    // env staging: threads 0..271 each own one (sample, env-ch)
    const int sA = tid / NENV, eA = tid - sA*NENV;
    const bool envth = (tid < 272);
    const float* envp = env + ((size_t)(s0 + (envth ? sA : 0))*NENV + (envth ? eA : 0))*TALL;
    float evA = envth ? envp[0] : 0.f;

    // ---------------- register weights (48 frags = 192 VGPR) ----------------
    bf16x8 W0r[16], WrA[16], WrB[16];
    float  lb1[4];
    #pragma unroll
    for (int g = 0; g < 4; ++g) {
        int gt = g*8 + wid;
        #pragma unroll
        for (int kb = 0; kb < 4; ++kb) {
            W0r[g*4+kb] = *(const bf16x8*)(wsb + ((size_t)(SEG_W0E  + (gt*4+kb)*64 + lane))*16);
            WrA[g*4+kb] = *(const bf16x8*)(wsb + ((size_t)(SEG_WIH1 + (gt*4+kb)*64 + lane))*16);
            WrB[g*4+kb] = *(const bf16x8*)(wsb + ((size_t)(SEG_WHH1 + (gt*4+kb)*64 + lane))*16);
        }
        int grow = gt*16 + cc;
        lb1[g] = enc_bih[512 + grow] + enc_bhh[512 + grow];
    }

    float c0r[4] = {0.f,0.f,0.f,0.f};
    float c1r[4] = {0.f,0.f,0.f,0.f};
    __syncthreads();

    // ================= encoder: 2 barriers/step =================
    #pragma unroll 1
    for (int t = 0; t < TCTX; ++t) {
        u16* h0w = (u16*)(smem + L_H0 + (t&1)*4352);
        u16* h0r = (u16*)(smem + L_H0 + ((t&1)^1)*4352);
        u16* h1w = (u16*)(smem + L_H1 + (t&1)*4352);
        u16* h1r = (u16*)(smem + L_H1 + ((t&1)^1)*4352);

        if (envth)    inps[sA*40 + eA]  = f2bf(evA);
        if (tid < 16) inps[tid*40 + 17] = f2bf(xblk[tid*24 + t]);
        __syncthreads();                                   // bar_inps
        if (envth && t+1 < TALL) evA = envp[t+1];

        bf16x8 ia = *(const bf16x8*)(inps + cc*40 + kg*8);
        f32x4 acc[4];
        #pragma unroll
        for (int g = 0; g < 4; ++g) {
            bf16x8 md = *(const bf16x8*)(MdL + ((size_t)((g*8+wid)*64 + lane))*8);
            acc[g] = __builtin_amdgcn_mfma_f32_16x16x32_bf16(ia, md, zero4, 0, 0, 0);
        }
        #pragma unroll
        for (int kb = 0; kb < 4; ++kb) {
            bf16x8 ha = *(const bf16x8*)(h0r + cc*136 + kb*32 + kg*8);
            #pragma unroll
            for (int g = 0; g < 4; ++g)
                acc[g] = __builtin_amdgcn_mfma_f32_16x16x32_bf16(ha, W0r[g*4+kb], acc[g], 0, 0, 0);
        }
        float h2[4];
        #pragma unroll
        for (int r = 0; r < 4; ++r) {
            float c2 = fmaf(sigf(acc[1][r]), c0r[r], sigf(acc[0][r])*tanhf_(acc[2][r]));
            c0r[r] = c2;
            h2[r] = sigf(acc[3][r])*tanhf_(c2);
        }
        #pragma unroll
        for (int r = 0; r < 4; ++r)
            h0w[(kg*4+r)*136 + wid*16 + cc] = f2bf(h2[r]);
        __syncthreads();                                   // bar_h0

        #pragma unroll
        for (int g = 0; g < 4; ++g) { f32x4 v = {lb1[g],lb1[g],lb1[g],lb1[g]}; acc[g] = v; }
        #pragma unroll
        for (int kb = 0; kb < 4; ++kb) {
            bf16x8 ha = *(const bf16x8*)(h0w + cc*136 + kb*32 + kg*8);
            #pragma unroll
            for (int g = 0; g < 4; ++g)
                acc[g] = __builtin_amdgcn_mfma_f32_16x16x32_bf16(ha, WrA[g*4+kb], acc[g], 0, 0, 0);
        }
        #pragma unroll
        for (int kb = 0; kb < 4; ++kb) {
            bf16x8 ha = *(const bf16x8*)(h1r + cc*136 + kb*32 + kg*8);
            #pragma unroll
            for (int g = 0; g < 4; ++g)
                acc[g] = __builtin_amdgcn_mfma_f32_16x16x32_bf16(ha, WrB[g*4+kb], acc[g], 0, 0, 0);
        }
        #pragma unroll
        for (int r = 0; r < 4; ++r) {
            float c2 = fmaf(sigf(acc[1][r]), c1r[r], sigf(acc[0][r])*tanhf_(acc[2][r]));
            c1r[r] = c2;
            h2[r] = sigf(acc[3][r])*tanhf_(c2);
        }
        #pragma unroll
        for (int r = 0; r < 4; ++r)
            h1w[(kg*4+r)*136 + wid*16 + cc] = f2bf(h2[r]);
        // no barrier: next bar_inps + bar_h0 cover publish before first read
    }

    __syncthreads();                                       // bar_T1: encoder state final

    // ================= transition =================
    {
        u16* hEnc = (u16*)(smem + L_H1 + 4352);            // h1 parity-1 = enc_state (t=23)
        f32x4 bD[4];
        #pragma unroll
        for (int g = 0; g < 4; ++g) bD[g] = zero4;
        #pragma unroll
        for (int kb = 0; kb < 4; ++kb) {
            bf16x8 ha = *(const bf16x8*)(hEnc + cc*136 + kb*32 + kg*8);
            #pragma unroll
            for (int g = 0; g < 4; ++g) {
                bf16x8 wb = *(const bf16x8*)(wsb + ((size_t)(SEG_WIHH + ((g*8+wid)*4+kb)*64 + lane))*16);
                bD[g] = __builtin_amdgcn_mfma_f32_16x16x32_bf16(ha, wb, bD[g], 0, 0, 0);
            }
        }
        #pragma unroll
        for (int g = 0; g < 4; ++g)
            *(f32x4*)(baseL + ((size_t)((wid*4+g)*64 + lane))*4) = bD[g];
    }
    #pragma unroll
    for (int g = 0; g < 4; ++g) {
        int gt = g*8 + wid;
        #pragma unroll
        for (int kb = 0; kb < 4; ++kb) {
            W0r[g*4+kb] = *(const bf16x8*)(wsb + ((size_t)(SEG_W0D  + (gt*4+kb)*64 + lane))*16);
            WrA[g*4+kb] = *(const bf16x8*)(wsb + ((size_t)(SEG_DWIH + (gt*4+kb)*64 + lane))*16);
            WrB[g*4+kb] = *(const bf16x8*)(wsb + ((size_t)(SEG_DWHH + (gt*4+kb)*64 + lane))*16);
        }
        int grow = gt*16 + cc;
        lb1[g] = dbih[grow] + dbhh[grow];
    }
    #pragma unroll
    for (int i = 0; i < 4; ++i)
        ((uint4*)(smem + L_MDL))[i*512 + tid] = ((const uint4*)wsb)[SEG_MDE + i*512 + tid];
    if (tid < SAMP) {
        float xv = xblk[tid*24 + 23];
        xcs[tid] = xv;
        inps[tid*40 + 17] = f2bf(xv);
    }
    const float b20 = mlp_b2[0], b21 = mlp_b2[1];
    const int hs = lane >> 2, hq = lane & 3;
    __syncthreads();                                       // bar_T2

    // ================= decoder: 4 barriers/step =================
    #pragma unroll 1
    for (int td = 0; td < HOR; ++td) {
        const int q = td & 1;                              // td=0 reads parity-1 (enc state)
        u16* h0w = (u16*)(smem + L_H0 + q*4352);
        u16* h0r = (u16*)(smem + L_H0 + (q^1)*4352);
        u16* h1w = (u16*)(smem + L_H1 + q*4352);
        u16* h1r = (u16*)(smem + L_H1 + (q^1)*4352);

        if (envth) inps[sA*40 + eA] = f2bf(evA);
        __syncthreads();                                   // bar_inps
        if (envth && TCTX+td+1 < TALL) evA = envp[TCTX+td+1];

        bf16x8 ia = *(const bf16x8*)(inps + cc*40 + kg*8);
        f32x4 acc[4];
        #pragma unroll
        for (int g = 0; g < 4; ++g) {
            f32x4 cb = *(const f32x4*)(baseL + ((size_t)((wid*4+g)*64 + lane))*4);
            bf16x8 md = *(const bf16x8*)(MdL + ((size_t)((g*8+wid)*64 + lane))*8);
            acc[g] = __builtin_amdgcn_mfma_f32_16x16x32_bf16(ia, md, cb, 0, 0, 0);
        }
        #pragma unroll
        for (int kb = 0; kb < 4; ++kb) {
            bf16x8 ha = *(const bf16x8*)(h0r + cc*136 + kb*32 + kg*8);
            #pragma unroll
            for (int g = 0; g < 4; ++g)
                acc[g] = __builtin_amdgcn_mfma_f32_16x16x32_bf16(ha, W0r[g*4+kb], acc[g], 0, 0, 0);
        }
        float h2[4];
        #pragma unroll
        for (int r = 0; r < 4; ++r) {
            float c2 = fmaf(sigf(acc[1][r]), c0r[r], sigf(acc[0][r])*tanhf_(acc[2][r]));
            c0r[r] = c2;
            h2[r] = sigf(acc[3][r])*tanhf_(c2);
        }
        #pragma unroll
        for (int r = 0; r < 4; ++r)
            h0w[(kg*4+r)*136 + wid*16 + cc] = f2bf(h2[r]);
        __syncthreads();                                   // bar_h0

        #pragma unroll
        for (int g = 0; g < 4; ++g) { f32x4 v = {lb1[g],lb1[g],lb1[g],lb1[g]}; acc[g] = v; }
        #pragma unroll
        for (int kb = 0; kb < 4; ++kb) {
            bf16x8 ha = *(const bf16x8*)(h0w + cc*136 + kb*32 + kg*8);
            #pragma unroll
            for (int g = 0; g < 4; ++g)
                acc[g] = __builtin_amdgcn_mfma_f32_16x16x32_bf16(ha, WrA[g*4+kb], acc[g], 0, 0, 0);
        }
        #pragma unroll
        for (int kb = 0; kb < 4; ++kb) {
            bf16x8 ha = *(const bf16x8*)(h1r + cc*136 + kb*32 + kg*8);
            #pragma unroll
            for (int g = 0; g < 4; ++g)
                acc[g] = __builtin_amdgcn_mfma_f32_16x16x32_bf16(ha, WrB[g*4+kb], acc[g], 0, 0, 0);
        }
        #pragma unroll
        for (int r = 0; r < 4; ++r) {
            float c2 = fmaf(sigf(acc[1][r]), c1r[r], sigf(acc[0][r])*tanhf_(acc[2][r]));
            c1r[r] = c2;
            h2[r] = sigf(acc[3][r])*tanhf_(c2);
        }
        #pragma unroll
        for (int r = 0; r < 4; ++r)
            h1w[(kg*4+r)*136 + wid*16 + cc] = f2bf(h2[r]);
        __syncthreads();                                   // bar_h1 (MLP consumes h1w)

        // ---- MLP (wave wid -> output units wid*16..+15) ----
        bf16x8 w1i = *(const bf16x8*)(W1Il + ((size_t)(wid*64 + lane))*8);
        f32x4 macc = __builtin_amdgcn_mfma_f32_16x16x32_bf16(ia, w1i, zero4, 0, 0, 0);
        #pragma unroll
        for (int kb = 0; kb < 4; ++kb) {
            bf16x8 ha = *(const bf16x8*)(h1w + cc*136 + kb*32 + kg*8);
            bf16x8 wb = *(const bf16x8*)(W1Hl + ((size_t)((wid*4+kb)*64 + lane))*8);
            macc = __builtin_amdgcn_mfma_f32_16x16x32_bf16(ha, wb, macc, 0, 0, 0);
        }
        #pragma unroll
        for (int r = 0; r < 4; ++r) {
            float z = macc[r];
            z = (z > 0.f) ? z : 0.01f*z;
            zms[(kg*4+r)*136 + wid*16 + cc] = f2bf(z);
        }
        __syncthreads();                                   // bar_z

        // ---- head: wave 0 only ----
        if (wid == 0) {
            float xch = xcs[hs];
            float a0 = 0.f, a1 = 0.f;
            #pragma unroll
            for (int c8 = 0; c8 < 4; ++c8) {
                bf16x8 z8 = *(const bf16x8*)(zms + hs*136 + hq*32 + c8*8);
                #pragma unroll
                for (int j = 0; j < 8; ++j) {
                    float zf = bf2f((u16)z8[j]);
                    int u = hq*32 + c8*8 + j;
                    a0 = fmaf(zf, w2l[u], a0);
                    a1 = fmaf(zf, w2l[128 + u], a1);
                }
            }
            a0 += __shfl_xor(a0, 1); a0 += __shfl_xor(a0, 2);
            a1 += __shfl_xor(a1, 1); a1 += __shfl_xor(a1, 2);
            float xn = xch + sigf(a0 + b20) - sigf(a1 + b21)*xch;
            if (hq == 0) {
                xcs[hs] = xn;
                inps[hs*40 + 17] = f2bf(xn);
                out[(size_t)(s0 + hs)*HOR + td] = xn;
            }
        }
        // next bar_inps publishes head's writes
    }
}

extern "C" void kernel_launch(void* const* d_in, const int* in_sizes, int n_in,
                              void* d_out, int out_size, void* d_ws, size_t ws_size,
                              hipStream_t stream)
{
    const float* x        = (const float*)d_in[0];
    const float* coords   = (const float*)d_in[1];
    const float* env      = (const float*)d_in[2];
    const float* areas    = (const float*)d_in[3];
    const float* W_enc_in = (const float*)d_in[4];
    const float* enc_Wih  = (const float*)d_in[5];
    const float* enc_Whh  = (const float*)d_in[6];
    const float* enc_bih  = (const float*)d_in[7];
    const float* enc_bhh  = (const float*)d_in[8];
    const float* W_dec_in = (const float*)d_in[9];
    const float* in_Wih   = (const float*)d_in[10];
    const float* in_Whh   = (const float*)d_in[11];
    const float* in_bih   = (const float*)d_in[12];
    const float* in_bhh   = (const float*)d_in[13];
    const float* dWih     = (const float*)d_in[14];
    const float* dWhh     = (const float*)d_in[15];
    const float* dbih     = (const float*)d_in[16];
    const float* dbhh     = (const float*)d_in[17];
    const float* mlp_W1   = (const float*)d_in[18];
    const float* mlp_b1   = (const float*)d_in[19];
    const float* mlp_W2   = (const float*)d_in[20];
    const float* mlp_b2   = (const float*)d_in[21];
    float* out = (float*)d_out;

    fold_kernel<<<dim3(250), dim3(256), 0, stream>>>(
        enc_Wih, enc_Whh, W_enc_in, in_Wih, in_Whh, W_dec_in,
        dWih, dWhh, mlp_W1, mlp_b1, enc_bih, enc_bhh, in_bih, in_bhh, d_ws);

    hipFuncSetAttribute((const void*)lstm_main,
                        hipFuncAttributeMaxDynamicSharedMemorySize, SMEM_TOTAL);
    lstm_main<<<dim3(NTOT/SAMP), dim3(512), SMEM_TOTAL, stream>>>(
        x, coords, env, areas, enc_bih, enc_bhh, dbih, dbhh, mlp_W2, mlp_b2, d_ws, out);
    (void)in_sizes; (void)n_in; (void)out_size; (void)ws_size;
}